// Round 5
// baseline (206.985 us; speedup 1.0000x reference)
//
#include <hip/hip_runtime.h>
#include <hip/hip_bf16.h>

// 3x3 conv pad=1 stride=1, NHWC fp32 -> bf16 MFMA implicit GEMM.
//   M = 32*56*56 = 100352, N = 256, K = 9*128 = 1152
// R9: two independent barrier domains per CU.  R6/R7/R8 (three different
// phase shapes) all plateau at 31-33% MfmaUtil with ~54% SIMD idle: with one
// 8-wave block per CU, the 2 waves on each SIMD are phase-locked by the same
// barrier -- their stall windows coincide and nothing covers them.  R9 runs
// 2 co-resident 4-wave blocks (tile 112x256, wave tile 112x64 -- identical
// per-wave work/ratio to R8), LDS 76 KiB/block so 2 blocks/CU: each SIMD
// hosts 1 wave from EACH block; when one block stalls at its barrier the
// other's MFMA burst fills the pipe.
// LDS: A regions depth 4 (112x32 bf16 = 7 KB x4), B regions depth 3
// (256x32 = 16 KB x3) = 76 KiB.  Ledger (phase i = kh i, 0..35):
//   STAGE_A(kh i+4) -> Areg i&3   [WAR: last read = RD prefetch at phase i-1]
//   STAGE_B(kh i+3) -> Breg i%3   [WAR: same]
//   RD(kh i+1)                    [A staged i-3, B staged i-2; both drained
//                                  by VMWAIT(6) at phase i-1 + its barrier]
//   MM(kh i) (28 MFMA, frags prefetched at phase i-1)
//   VMWAIT(6); BARRIER            [drains phase i-1's 6 loads]
// 6 loads/wave/phase uniform (A: 2 with wave-3 dup; B: 4).  Stages past
// kh=35 are source-CLAMPED duplicates into dead regions (keeps the per-wave
// vmcnt ledger uniform; dests in-bounds).  Final VMWAIT(0) stops in-flight
// DMA from landing in a successor block's LDS.  12-phase static body
// (LCM of A-depth 4, B-depth 3, frag-set parity 2).

#define NIMG 32
#define HH 56
#define WW 56
#define PH 58
#define PW 58
#define CIN 128
#define COUT 256
#define KTOT 1152
#define PAD_ELEMS (NIMG * PH * PW * CIN)

#define BM 112
#define NPHASE 36                        // kh phases (K=32 each)
#define NBLK ((NIMG * HH * WW) / BM)     // 896 = 8 * 112

#define AREG_SZ 3584                     // shorts: 112 rows x 32 k
#define BREG_BASE 14336                  // 4 * AREG_SZ
#define BREG_SZ 8192                     // shorts: 256 rows x 32 k

typedef __attribute__((ext_vector_type(8))) short bf16x8;
typedef __attribute__((ext_vector_type(4))) short s16x4;
typedef __attribute__((ext_vector_type(4))) float f32x4;

__device__ __forceinline__ short f2bf(float x) {
    union { __hip_bfloat16 b; short s; } u;
    u.b = __float2bfloat16(x);
    return u.s;
}

typedef const void __attribute__((address_space(1)))* gas1_t;
typedef void __attribute__((address_space(3)))* las3_t;
__device__ __forceinline__ void async16(short* lds_p, const short* g) {
    __builtin_amdgcn_global_load_lds((gas1_t)g, (las3_t)lds_p, 16, 0, 0);
}

// ---- pack 1: fp32 NHWC -> padded bf16 (32,58,58,128), zero halo -------------
__global__ __launch_bounds__(256) void pack_input(const float* __restrict__ in,
                                                  short* __restrict__ pad) {
    const int tid  = blockIdx.x * 256 + threadIdx.x;
    const int flat = tid * 8;
    const int c8   = flat & (CIN - 1);
    const int rest = flat >> 7;
    const int iw   = rest % PW;
    const int r2   = rest / PW;
    const int ih   = r2 % PH;
    const int img  = r2 / PH;
    bf16x8 v = (bf16x8)0;
    if (ih >= 1 && ih <= HH && iw >= 1 && iw <= WW) {
        const float* p = in + (((size_t)(img * HH + ih - 1) * WW + (iw - 1)) * CIN + c8);
        const float4 x0 = *(const float4*)p;
        const float4 x1 = *(const float4*)(p + 4);
        v.s0 = f2bf(x0.x); v.s1 = f2bf(x0.y); v.s2 = f2bf(x0.z); v.s3 = f2bf(x0.w);
        v.s4 = f2bf(x1.x); v.s5 = f2bf(x1.y); v.s6 = f2bf(x1.z); v.s7 = f2bf(x1.w);
    }
    *(bf16x8*)(pad + flat) = v;
}

// ---- pack 2: weights (K=1152, N=256) fp32 -> bf16 transposed [n][k] ---------
__global__ __launch_bounds__(256) void pack_wgt(const float* __restrict__ w,
                                                short* __restrict__ wt) {
    __shared__ short tile[32][33];
    const int k0 = blockIdx.x * 32;
    const int n0 = blockIdx.y * 32;
    const int t  = threadIdx.x;
    {
        const int kl  = t >> 3;
        const int nl4 = (t & 7) * 4;
        const float4 x = *(const float4*)(w + (size_t)(k0 + kl) * COUT + n0 + nl4);
        tile[kl][nl4 + 0] = f2bf(x.x);
        tile[kl][nl4 + 1] = f2bf(x.y);
        tile[kl][nl4 + 2] = f2bf(x.z);
        tile[kl][nl4 + 3] = f2bf(x.w);
    }
    __syncthreads();
    {
        const int nl  = t >> 3;
        const int kl4 = (t & 7) * 4;
        s16x4 v;
        v.x = tile[kl4 + 0][nl];
        v.y = tile[kl4 + 1][nl];
        v.z = tile[kl4 + 2][nl];
        v.w = tile[kl4 + 3][nl];
        *(s16x4*)(wt + (size_t)(n0 + nl) * KTOT + k0 + kl4) = v;
    }
}

// ---- GEMM: 112x256 tile, 4 waves, 2 blocks/CU, 16x16x32 bf16 MFMA ----------
#define FENCE() asm volatile("" ::: "memory")
#define BARRIER() do { FENCE(); __builtin_amdgcn_s_barrier(); FENCE(); } while (0)
#define VMWAIT(N) asm volatile("s_waitcnt vmcnt(" #N ")" ::: "memory")

__global__ __launch_bounds__(256, 2) void conv_mfma(const short* __restrict__ apad,
                                                    const short* __restrict__ bwt,
                                                    const float* __restrict__ bias,
                                                    float* __restrict__ out) {
    __shared__ short lds[38912];   // 76 KiB -> 2 blocks/CU

    const int t  = threadIdx.x;    // 0..255
    const int l  = t & 63;
    const int w  = t >> 6;         // 0..3  (wave = N-quarter)
    const int fr = l & 15;
    const int fq = l >> 4;

    // fragment lane offset (shorts), swizzle folded in (frag row base is a
    // multiple of 16 so (row>>1)&3 == (fr>>1)&3):
    const int laneoff = fr * 32 + ((fq ^ ((fr >> 1) & 3))) * 8;
    const int bfb = w * 2048;      // B frag base: (w*64)*32 shorts
    // staging: lane covers 16B slot (l&3) of row chunk*16 + (l>>2); logical
    // kchunk = (l&3) ^ ((row>>1)&3) = (l&3) ^ ((l>>3)&3) for all our chunks.
    const int kcs = (l & 3) ^ ((l >> 3) & 3);

    const int bid = blockIdx.x;
    const int swz = (bid & 7) * (NBLK / 8) + (bid >> 3);   // 896 = 8*112
    const int m0  = swz * BM;

    // A staging rows: load1 -> row r0 = t>>2 (0..63, chunk w);
    // load2 -> row 64+r0 (waves 0..2, chunks 4..6); wave 3 duplicates load1.
    const int r0 = t >> 2;
    int abase0, abase1;
    {
        int m = m0 + r0;
        int img = m / (HH * WW), rem = m - img * (HH * WW);
        int oh = rem / WW, ow = rem - oh * WW;
        abase0 = ((img * PH + oh) * PW + ow) * CIN;
        if (w < 3) {
            m = m0 + r0 + 64;      // r0 <= 47 here -> row <= 111
            img = m / (HH * WW); rem = m - img * (HH * WW);
            oh = rem / WW; ow = rem - oh * WW;
            abase1 = ((img * PH + oh) * PW + ow) * CIN;
        } else {
            abase1 = abase0;       // wave 3: benign duplicate
        }
    }
    const int a2lds  = (w < 3) ? (4 + w) * 512 : 3 * 512;
    const int bbaseB = (w * 64 + (l >> 2)) * KTOT;   // + j*16 rows = +j*18432

    f32x4 acc[7][4];
#pragma unroll
    for (int i = 0; i < 7; ++i)
#pragma unroll
        for (int j = 0; j < 4; ++j) { f32x4 z = {0.f, 0.f, 0.f, 0.f}; acc[i][j] = z; }

    // double-named fragment sets (disjoint live ranges -> allocator coalesces)
    bf16x8 Aa[7], Ab[7], Ba[4], Bb[4];

    // kh K (0..35): tap = K>>2, channel offset (K&3)*32.  Source kh CLAMPED
    // to 35 past the end (dead-region duplicate); dest region RG literal.
#define STAGE_A(K, RG) do {                                                   \
        const int _kk  = (K) > 35 ? 35 : (K);                                 \
        const int _tap = _kk >> 2;                                            \
        const int _fh  = (_tap * 11) >> 5;   /* /3 for 0..8 */                \
        const int _fw  = _tap - 3 * _fh;                                      \
        const int _off = (_fh * PW + _fw) * CIN + (_kk & 3) * 32 + kcs * 8;   \
        short* _l = lds + (RG) * AREG_SZ;                                     \
        async16(_l + w * 512, apad + abase0 + _off);                          \
        async16(_l + a2lds,   apad + abase1 + _off);                          \
    } while (0)

#define STAGE_B(K, RG) do {                                                   \
        const int _kk  = (K) > 35 ? 35 : (K);                                 \
        const int _off = _kk * 32 + kcs * 8;                                  \
        short* _l = lds + BREG_BASE + (RG) * BREG_SZ + w * 2048;              \
        async16(_l,        bwt + bbaseB + _off);                              \
        async16(_l + 512,  bwt + bbaseB + 18432 + _off);                      \
        async16(_l + 1024, bwt + bbaseB + 36864 + _off);                      \
        async16(_l + 1536, bwt + bbaseB + 55296 + _off);                      \
    } while (0)

    // read all 11 fragments (A region AR, B region BR) into set (AF, BF)
#define RD(AF, BF, AR, BR) do {                                               \
        const short* _a = lds + (AR) * AREG_SZ;                               \
        const short* _b = lds + BREG_BASE + (BR) * BREG_SZ + bfb;             \
        _Pragma("unroll")                                                     \
        for (int _i = 0; _i < 7; ++_i)                                        \
            (AF)[_i] = *(const bf16x8*)(_a + _i * 512 + laneoff);             \
        _Pragma("unroll")                                                     \
        for (int _j = 0; _j < 4; ++_j)                                        \
            (BF)[_j] = *(const bf16x8*)(_b + _j * 512 + laneoff);             \
    } while (0)

#define MM(AF, BF) do {                                                       \
        __builtin_amdgcn_s_setprio(1);                                        \
        _Pragma("unroll")                                                     \
        for (int _i = 0; _i < 7; ++_i)                                        \
            _Pragma("unroll")                                                 \
            for (int _j = 0; _j < 4; ++_j)                                    \
                acc[_i][_j] = __builtin_amdgcn_mfma_f32_16x16x32_bf16(        \
                    (AF)[_i], (BF)[_j], acc[_i][_j], 0, 0, 0);                \
        __builtin_amdgcn_s_setprio(0);                                        \
    } while (0)

    // one phase; regions are compile-time literals from the 12-phase body
#define PHX(KH, ARS, BRS, ARR, BRR, AFc, BFc, AFn, BFn) do {                  \
        STAGE_A((KH) + 4, ARS);                                               \
        STAGE_B((KH) + 3, BRS);                                               \
        RD(AFn, BFn, ARR, BRR);                                               \
        MM(AFc, BFc);                                                         \
        VMWAIT(6);                                                            \
        BARRIER();                                                            \
    } while (0)

    // prologue: A kh0..3 (8 loads) + B kh0..2 (12 loads); VMWAIT(4) completes
    // A0-3,B0,B1 (leaves B2); barrier; RD(kh0); barrier (RD before phase-0's
    // overwrite of region 0).
    STAGE_A(0, 0); STAGE_A(1, 1); STAGE_A(2, 2); STAGE_A(3, 3);
    STAGE_B(0, 0); STAGE_B(1, 1); STAGE_B(2, 2);
    VMWAIT(4);
    BARRIER();
    RD(Aa, Ba, 0, 0);
    BARRIER();

    // 36 phases, 12-phase static body (A regions mod 4, B mod 3, sets mod 2)
#pragma unroll 1
    for (int jb = 0; jb < NPHASE; jb += 12) {
        PHX(jb + 0,  0, 0, 1, 1, Aa, Ba, Ab, Bb);
        PHX(jb + 1,  1, 1, 2, 2, Ab, Bb, Aa, Ba);
        PHX(jb + 2,  2, 2, 3, 0, Aa, Ba, Ab, Bb);
        PHX(jb + 3,  3, 0, 0, 1, Ab, Bb, Aa, Ba);
        PHX(jb + 4,  0, 1, 1, 2, Aa, Ba, Ab, Bb);
        PHX(jb + 5,  1, 2, 2, 0, Ab, Bb, Aa, Ba);
        PHX(jb + 6,  2, 0, 3, 1, Aa, Ba, Ab, Bb);
        PHX(jb + 7,  3, 1, 0, 2, Ab, Bb, Aa, Ba);
        PHX(jb + 8,  0, 2, 1, 0, Aa, Ba, Ab, Bb);
        PHX(jb + 9,  1, 0, 2, 1, Ab, Bb, Aa, Ba);
        PHX(jb + 10, 2, 1, 3, 2, Aa, Ba, Ab, Bb);
        PHX(jb + 11, 3, 2, 0, 0, Ab, Bb, Aa, Ba);
    }

    VMWAIT(0);   // don't let clamped dead-region DMA land in a successor block

    // ---- epilogue: bias + ReLU. D: col(N)=lane&15, row(M)=fq*4+reg (m89)
#pragma unroll
    for (int j = 0; j < 4; ++j) {
        const int n  = w * 64 + j * 16 + fr;
        const float bj = bias[n];
#pragma unroll
        for (int i = 0; i < 7; ++i) {
            const int mr = m0 + i * 16 + fq * 4;
#pragma unroll
            for (int r = 0; r < 4; ++r) {
                const float v = acc[i][j][r] + bj;
                out[(size_t)(mr + r) * COUT + n] = v > 0.f ? v : 0.f;
            }
        }
    }
#undef STAGE_A
#undef STAGE_B
#undef RD
#undef MM
#undef PHX
}

extern "C" void kernel_launch(void* const* d_in, const int* in_sizes, int n_in,
                              void* d_out, int out_size, void* d_ws, size_t ws_size,
                              hipStream_t stream) {
    const float* in   = (const float*)d_in[0];
    const float* wgt  = (const float*)d_in[1];
    const float* bias = (const float*)d_in[2];
    float* out = (float*)d_out;

    short* pad = (short*)d_ws;
    short* wt  = (short*)d_ws + PAD_ELEMS;

    pack_input<<<PAD_ELEMS / 8 / 256, 256, 0, stream>>>(in, pad);
    pack_wgt<<<dim3(KTOT / 32, COUT / 32), 256, 0, stream>>>(wgt, wt);

    conv_mfma<<<NBLK, 256, 0, stream>>>(pad, wt, bias, out);
}

// Round 6
// 203.330 us; speedup vs baseline: 1.0180x; 1.0180x over previous
//
#include <hip/hip_runtime.h>
#include <hip/hip_bf16.h>

// 3x3 conv pad=1 stride=1, NHWC fp32 -> bf16 MFMA implicit GEMM.
//   M = 32*56*56 = 100352, N = 256, K = 9*128 = 1152
// R10: persistent A window in LDS.  Evidence: R6/R7/R8 (same staged
// bytes/K-tile, different schedules) were invariant at 75-79us; R9 (+50%
// staged bytes/FLOP) regressed 22% -> the global->LDS DMA path is the
// binding resource (495 MB = 6.6 TB/s fill traffic/dispatch), and 45% of it
// is the 9x re-staging of A (one per tap).  A block's unique A footprint is
// 6 padded rows x 58 cols x 128 ch = 89 KB -> stage ONCE in the prologue;
// MFMA A-fragments read it directly with per-lane (row,col)-precomputed
// addresses + per-phase tap offset.  K-loop stages only B: 2 loads/wave/
// phase, depth-3 regions, VMWAIT(2)/phase.
// Ledger: phase p stages B(p+3)->region (p+3)%3; VMWAIT(2) at p drains the
// stage issued at p-1 = B(p+2); RD at p prefetches kh p+1 (staged p-2,
// drained p-1 + barrier).  Region overwrite at p hits B(p)'s region, last
// ds_read at p-1, one barrier back (same WAR exposure as R5-R8, all passed).
// Prologue: A(11 loads) + B0,B1,B2; VMWAIT(2) drains A+B0+B1.
// A swizzle: phys 16B chunk p at cell (ih,iw) holds logical chunk
// p ^ (iw&15) (16 chunks = 256 B per cell).  DMA dest linear, source
// pre-swizzled (both-sides rule).  Fragment read: 16 lanes have consecutive
// iw -> phys&7 covers each bank-group 2x = 2-way = free (m136).
// B side (staging, swizzle, reads) verbatim from R8 (refcheck-passed).

#define NIMG 32
#define HH 56
#define WW 56
#define PH 58
#define PW 58
#define CIN 128
#define COUT 256
#define KTOT 1152
#define PAD_ELEMS (NIMG * PH * PW * CIN)   // 13,778,944 shorts

#define BM 224
#define NPHASE 36                        // kh phases (K=32 each)
#define NBLK ((NIMG * HH * WW) / BM)     // 448 = 8 * 56

// LDS (shorts): A window 5632 chunks x 8 = 45056 (6x58 cells x 256B, linear
// chunk index (ih*58+iw)*16+phys, incl. 64-chunk staging slack);
// B: 3 regions x 8192 (256 rows x 32 k).  Total 69632 shorts = 136 KiB.
#define B_BASE 45056
#define BREG_SZ 8192
#define AWIN_CHUNKS 5568                 // real window; staged 5632 (11x512)

#define NPACK_IN 6728                    // PAD_ELEMS/8/256
#define NPACK_WGT 288                    // (1152/32)*(256/32)

typedef __attribute__((ext_vector_type(8))) short bf16x8;
typedef __attribute__((ext_vector_type(4))) short s16x4;
typedef __attribute__((ext_vector_type(4))) float f32x4;

__device__ __forceinline__ short f2bf(float x) {
    union { __hip_bfloat16 b; short s; } u;
    u.b = __float2bfloat16(x);
    return u.s;
}

typedef const void __attribute__((address_space(1)))* gas1_t;
typedef void __attribute__((address_space(3)))* las3_t;
__device__ __forceinline__ void async16(short* lds_p, const short* g) {
    __builtin_amdgcn_global_load_lds((gas1_t)g, (las3_t)lds_p, 16, 0, 0);
}

// ---- fused pack: input fp32->padded bf16  +  weights fp32->bf16 [n][k] -----
__global__ __launch_bounds__(256) void pack_fused(const float* __restrict__ in,
                                                  short* __restrict__ pad,
                                                  const float* __restrict__ wsrc,
                                                  short* __restrict__ wt) {
    __shared__ short tile[32][33];
    const int bx = blockIdx.x;
    const int t  = threadIdx.x;
    if (bx < NPACK_IN) {
        const int tid  = bx * 256 + t;
        const int flat = tid * 8;
        const int c8   = flat & (CIN - 1);
        const int rest = flat >> 7;
        const int iw   = rest % PW;
        const int r2   = rest / PW;
        const int ih   = r2 % PH;
        const int img  = r2 / PH;
        bf16x8 v = (bf16x8)0;
        if (ih >= 1 && ih <= HH && iw >= 1 && iw <= WW) {
            const float* p = in + (((size_t)(img * HH + ih - 1) * WW + (iw - 1)) * CIN + c8);
            const float4 x0 = *(const float4*)p;
            const float4 x1 = *(const float4*)(p + 4);
            v.s0 = f2bf(x0.x); v.s1 = f2bf(x0.y); v.s2 = f2bf(x0.z); v.s3 = f2bf(x0.w);
            v.s4 = f2bf(x1.x); v.s5 = f2bf(x1.y); v.s6 = f2bf(x1.z); v.s7 = f2bf(x1.w);
        }
        *(bf16x8*)(pad + flat) = v;
    } else {
        const int wb = bx - NPACK_IN;
        const int k0 = (wb % 36) * 32;
        const int n0 = (wb / 36) * 32;
        {
            const int kl  = t >> 3;
            const int nl4 = (t & 7) * 4;
            const float4 x = *(const float4*)(wsrc + (size_t)(k0 + kl) * COUT + n0 + nl4);
            tile[kl][nl4 + 0] = f2bf(x.x);
            tile[kl][nl4 + 1] = f2bf(x.y);
            tile[kl][nl4 + 2] = f2bf(x.z);
            tile[kl][nl4 + 3] = f2bf(x.w);
        }
        __syncthreads();
        {
            const int nl  = t >> 3;
            const int kl4 = (t & 7) * 4;
            s16x4 v;
            v.x = tile[kl4 + 0][nl];
            v.y = tile[kl4 + 1][nl];
            v.z = tile[kl4 + 2][nl];
            v.w = tile[kl4 + 3][nl];
            *(s16x4*)(wt + (size_t)(n0 + nl) * KTOT + k0 + kl4) = v;
        }
    }
}

// ---- GEMM: 224x256 tile, persistent-A LDS, B-only phase staging ------------
#define FENCE() asm volatile("" ::: "memory")
#define BARRIER() do { FENCE(); __builtin_amdgcn_s_barrier(); FENCE(); } while (0)
#define VMWAIT(N) asm volatile("s_waitcnt vmcnt(" #N ")" ::: "memory")

__global__ __launch_bounds__(512, 2) void conv_mfma(const short* __restrict__ apad,
                                                    const short* __restrict__ bwt,
                                                    const float* __restrict__ bias,
                                                    float* __restrict__ out) {
    __shared__ short lds[69632];   // 136 KiB

    const int t  = threadIdx.x;    // 0..511
    const int l  = t & 63;
    const int w  = t >> 6;         // 0..7
    const int wm = w >> 2;         // 0..1  (M half: 112 rows)
    const int wn = w & 3;          // 0..3  (N quarter: 64 cols)
    const int fr = l & 15;
    const int fq = l >> 4;

    // B fragment lane offset (R8-proven): row=fr, phys chunk fq^((fr>>1)&3)
    const int laneoff = fr * 32 + ((fq ^ ((fr >> 1) & 3))) * 8;
    const int bfb = wn * 2048;     // B frag base: (wn*64)*32 shorts
    // B staging: thread t -> row t>>2, phys chunk t&3, logical kcs
    const int kcs = (t & 3) ^ ((t >> 3) & 3);

    const int bid = blockIdx.x;
    const int swz = (bid & 7) * (NBLK / 8) + (bid >> 3);   // 448 = 8*56, bijective
    const int m0  = swz * BM;

    // block geometry: 224 | 3136 -> one image, 4 full output rows oh0..oh0+3
    const int img = m0 / (HH * WW);
    const int oh0 = (m0 - img * (HH * WW)) / WW;
    const int gwin = ((img * PH + oh0) * PW) * CIN;   // A window global base

    // per-lane A fragment geometry: fragment i covers m rows m0+wm*112+i*16+fr
    int abase[7], aow[7];
#pragma unroll
    for (int i = 0; i < 7; ++i) {
        const int mm = (m0 - img * (HH * WW)) + wm * 112 + i * 16 + fr;
        const int oh = mm / WW;
        const int ow = mm - oh * WW;
        abase[i] = ((oh - oh0) * PW + ow) * CIN;   // shorts (cell stride 128)
        aow[i]   = ow;
    }

    // B staging row bases (rows r0 and r0+128 of the 256-row B panel)
    const int r0 = t >> 2;
    const int bbase0 = r0 * KTOT;
    const int bbase1 = (r0 + 128) * KTOT;

    f32x4 acc[7][4];
#pragma unroll
    for (int i = 0; i < 7; ++i)
#pragma unroll
        for (int j = 0; j < 4; ++j) { f32x4 z = {0.f, 0.f, 0.f, 0.f}; acc[i][j] = z; }

    bf16x8 Aa[7], Ab[7], Ba[4], Bb[4];

#define STAGE_B(K, RG) do {                                                   \
        const int _kk  = (K) > 35 ? 35 : (K);                                 \
        const int _off = _kk * 32 + kcs * 8;                                  \
        short* _l = lds + B_BASE + (RG) * BREG_SZ;                            \
        async16(_l + w * 512,        bwt + bbase0 + _off);                    \
        async16(_l + 4096 + w * 512, bwt + bbase1 + _off);                    \
    } while (0)

    // A fragments for kh-phase K1 from the persistent window.
    // kh: tap = K1>>2 (fh,fw), ch quarter q = K1&3; lane reads logical chunk
    // q*4+fq at cell (oh-oh0+fh, ow+fw); phys = logical ^ (iw&15).
#define RD_A(AF, K1) do {                                                     \
        const int _kk  = (K1) > 35 ? 35 : (K1);                               \
        const int _tap = _kk >> 2;                                            \
        const int _q   = _kk & 3;                                             \
        const int _fh  = (_tap * 11) >> 5;                                    \
        const int _fw  = _tap - 3 * _fh;                                      \
        const int _toff = (_fh * PW + _fw) * CIN;                             \
        const int _q4 = (_q << 2) | fq;                                       \
        _Pragma("unroll")                                                     \
        for (int _i = 0; _i < 7; ++_i) {                                      \
            const int _phys = _q4 ^ ((aow[_i] + _fw) & 15);                   \
            (AF)[_i] = *(const bf16x8*)(lds + abase[_i] + _toff + (_phys << 3)); \
        }                                                                     \
    } while (0)

#define RD_B(BF, RG) do {                                                     \
        const short* _b = lds + B_BASE + (RG) * BREG_SZ + bfb;                \
        _Pragma("unroll")                                                     \
        for (int _j = 0; _j < 4; ++_j)                                        \
            (BF)[_j] = *(const bf16x8*)(_b + _j * 512 + laneoff);             \
    } while (0)

#define MM(AF, BF) do {                                                       \
        __builtin_amdgcn_s_setprio(1);                                        \
        _Pragma("unroll")                                                     \
        for (int _i = 0; _i < 7; ++_i)                                        \
            _Pragma("unroll")                                                 \
            for (int _j = 0; _j < 4; ++_j)                                    \
                acc[_i][_j] = __builtin_amdgcn_mfma_f32_16x16x32_bf16(        \
                    (AF)[_i], (BF)[_j], acc[_i][_j], 0, 0, 0);                \
        __builtin_amdgcn_s_setprio(0);                                        \
    } while (0)

    // phase: stage-B | prefetch next kh frags | 28 MFMA | VMWAIT(2) | barrier
#define PHZ(C, K, AFc, BFc, AFn, BFn) do {                                    \
        STAGE_B((K) + 3, (C) % 3);                                            \
        RD_A(AFn, (K) + 1);                                                   \
        RD_B(BFn, ((C) + 1) % 3);                                             \
        MM(AFc, BFc);                                                         \
        VMWAIT(2);                                                            \
        BARRIER();                                                            \
    } while (0)

    // ---- prologue: stage A window (11 x 512 chunks; dest linear, source
    // pre-swizzled; lanes past chunk 5567 clamp SOURCE only) + B kh0..2.
#pragma unroll
    for (int j = 0; j < 11; ++j) {
        const int P  = j * 512 + t;
        const int Pc = P > (AWIN_CHUNKS - 1) ? (AWIN_CHUNKS - 1) : P;
        const int cell = Pc >> 4;
        const int iw   = cell % PW;
        const int src  = cell * CIN + (((Pc & 15) ^ (iw & 15)) << 3);
        async16(lds + P * 8, apad + gwin + src);
    }
    STAGE_B(0, 0); STAGE_B(1, 1); STAGE_B(2, 2);
    VMWAIT(2);                 // drains A(11) + B0 + B1; leaves B2 in flight
    BARRIER();
    RD_A(Aa, 0); RD_B(Ba, 0);
    BARRIER();

    // ---- main loop: 36 phases, 6-phase static body (B regions mod 3,
    // frag sets mod 2; jb multiple of 6 keeps both literal)
#pragma unroll 1
    for (int jb = 0; jb < NPHASE; jb += 6) {
        PHZ(0, jb + 0, Aa, Ba, Ab, Bb);
        PHZ(1, jb + 1, Ab, Bb, Aa, Ba);
        PHZ(2, jb + 2, Aa, Ba, Ab, Bb);
        PHZ(3, jb + 3, Ab, Bb, Aa, Ba);
        PHZ(4, jb + 4, Aa, Ba, Ab, Bb);
        PHZ(5, jb + 5, Ab, Bb, Aa, Ba);
    }

    VMWAIT(0);   // all DMA (incl. clamped dummies) landed before block exits

    // ---- epilogue: bias + ReLU. D: col(N)=lane&15, row(M)=fq*4+reg (m89)
#pragma unroll
    for (int j = 0; j < 4; ++j) {
        const int n  = wn * 64 + j * 16 + fr;
        const float bj = bias[n];
#pragma unroll
        for (int i = 0; i < 7; ++i) {
            const int mr = m0 + wm * 112 + i * 16 + fq * 4;
#pragma unroll
            for (int r = 0; r < 4; ++r) {
                const float v = acc[i][j][r] + bj;
                out[(size_t)(mr + r) * COUT + n] = v > 0.f ? v : 0.f;
            }
        }
    }
#undef STAGE_B
#undef RD_A
#undef RD_B
#undef MM
#undef PHZ
}

extern "C" void kernel_launch(void* const* d_in, const int* in_sizes, int n_in,
                              void* d_out, int out_size, void* d_ws, size_t ws_size,
                              hipStream_t stream) {
    const float* in   = (const float*)d_in[0];
    const float* wgt  = (const float*)d_in[1];
    const float* bias = (const float*)d_in[2];
    float* out = (float*)d_out;

    short* pad = (short*)d_ws;
    short* wt  = (short*)d_ws + PAD_ELEMS;

    pack_fused<<<NPACK_IN + NPACK_WGT, 256, 0, stream>>>(in, pad, wgt, wt);

    conv_mfma<<<NBLK, 512, 0, stream>>>(pad, wt, bias, out);
}

// Round 7
// 201.620 us; speedup vs baseline: 1.0266x; 1.0085x over previous
//
#include <hip/hip_runtime.h>
#include <hip/hip_bf16.h>

// 3x3 conv pad=1 stride=1, NHWC fp32 -> bf16 MFMA implicit GEMM.
//   M = 32*56*56 = 100352, N = 256, K = 9*128 = 1152
// R11: fuse input packing INTO the GEMM.  Ablation across R6-R10: schedule
// shape invariant (75-79us), staged-bytes up OR down both regress -> conv
// core pinned ~75us/32%; meanwhile total-minus-conv is a FIXED ~112-125us
// every round, of which pack_input (79 MB pass + 27.6 MB intermediate +
// launch gap) is the deletable part.  R10's persistent-A window enables it:
// the prologue reg-stages each block's 6x58x128 window DIRECTLY from fp32
// input (coalesced float4 x2 per chunk, cvt, halo-zero predicate, ds_write
// to swizzled dest -- reg-staging writes the swizzle directly, m173), so the
// padded intermediate and its pack kernel die.  In-loop pipeline = R10
// verbatim (B-only staging via global_load_lds, depth-3 regions,
// VMWAIT(2)/phase ledger, refcheck-passed).  New sync rule: explicit
// lgkmcnt(0) before the prologue barrier (raw s_barrier drains nothing;
// other waves must see the A ds_writes).

#define NIMG 32
#define HH 56
#define WW 56
#define CIN 128
#define COUT 256
#define KTOT 1152

#define BM 224
#define NPHASE 36                        // kh phases (K=32 each)
#define NBLK ((NIMG * HH * WW) / BM)     // 448 = 8 * 56

// LDS (shorts): A window 5632 chunks x 8 = 45056 (6x58 cells x 256 B,
// chunk = (cell)*16 + phys, phys = logical ^ (iw&15); 64-chunk slack);
// B: 3 regions x 8192 (256 rows x 32 k).  Total 69632 shorts = 136 KiB.
#define B_BASE 45056
#define BREG_SZ 8192
#define AWIN_CHUNKS 5568                 // real window; slack to 5632 (11x512)

typedef __attribute__((ext_vector_type(8))) short bf16x8;
typedef __attribute__((ext_vector_type(4))) short s16x4;
typedef __attribute__((ext_vector_type(4))) float f32x4;

__device__ __forceinline__ short f2bf(float x) {
    union { __hip_bfloat16 b; short s; } u;
    u.b = __float2bfloat16(x);
    return u.s;
}

typedef const void __attribute__((address_space(1)))* gas1_t;
typedef void __attribute__((address_space(3)))* las3_t;
__device__ __forceinline__ void async16(short* lds_p, const short* g) {
    __builtin_amdgcn_global_load_lds((gas1_t)g, (las3_t)lds_p, 16, 0, 0);
}

// ---- pack: weights (K=1152, N=256) fp32 -> bf16 transposed [n][k] ----------
__global__ __launch_bounds__(256) void pack_wgt(const float* __restrict__ w,
                                                short* __restrict__ wt) {
    __shared__ short tile[32][33];
    const int k0 = blockIdx.x * 32;
    const int n0 = blockIdx.y * 32;
    const int t  = threadIdx.x;
    {
        const int kl  = t >> 3;
        const int nl4 = (t & 7) * 4;
        const float4 x = *(const float4*)(w + (size_t)(k0 + kl) * COUT + n0 + nl4);
        tile[kl][nl4 + 0] = f2bf(x.x);
        tile[kl][nl4 + 1] = f2bf(x.y);
        tile[kl][nl4 + 2] = f2bf(x.z);
        tile[kl][nl4 + 3] = f2bf(x.w);
    }
    __syncthreads();
    {
        const int nl  = t >> 3;
        const int kl4 = (t & 7) * 4;
        s16x4 v;
        v.x = tile[kl4 + 0][nl];
        v.y = tile[kl4 + 1][nl];
        v.z = tile[kl4 + 2][nl];
        v.w = tile[kl4 + 3][nl];
        *(s16x4*)(wt + (size_t)(n0 + nl) * KTOT + k0 + kl4) = v;
    }
}

// ---- GEMM: 224x256 tile, fused-pack persistent-A, B-only phase staging -----
#define FENCE() asm volatile("" ::: "memory")
#define BARRIER() do { FENCE(); __builtin_amdgcn_s_barrier(); FENCE(); } while (0)
#define VMWAIT(N) asm volatile("s_waitcnt vmcnt(" #N ")" ::: "memory")
#define LGKMWAIT0() asm volatile("s_waitcnt lgkmcnt(0)" ::: "memory")

__global__ __launch_bounds__(512, 2) void conv_mfma(const float* __restrict__ in,
                                                    const short* __restrict__ bwt,
                                                    const float* __restrict__ bias,
                                                    float* __restrict__ out) {
    __shared__ short lds[69632];   // 136 KiB

    const int t  = threadIdx.x;    // 0..511
    const int l  = t & 63;
    const int w  = t >> 6;         // 0..7
    const int wm = w >> 2;         // 0..1  (M half: 112 rows)
    const int wn = w & 3;          // 0..3  (N quarter: 64 cols)
    const int fr = l & 15;
    const int fq = l >> 4;

    // B fragment lane offset (R8-proven): row=fr, phys chunk fq^((fr>>1)&3)
    const int laneoff = fr * 32 + ((fq ^ ((fr >> 1) & 3))) * 8;
    const int bfb = wn * 2048;     // B frag base: (wn*64)*32 shorts
    // B staging: thread t -> row t>>2, phys chunk t&3, logical kcs
    const int kcs = (t & 3) ^ ((t >> 3) & 3);

    const int bid = blockIdx.x;
    const int swz = (bid & 7) * (NBLK / 8) + (bid >> 3);   // 448 = 8*56, bijective
    const int m0  = swz * BM;

    // block geometry: one image, 4 full output rows oh0..oh0+3
    const int img = m0 / (HH * WW);
    const int oh0 = (m0 - img * (HH * WW)) / WW;

    // per-lane A fragment geometry: fragment i covers m rows m0+wm*112+i*16+fr
    int abase[7], aow[7];
#pragma unroll
    for (int i = 0; i < 7; ++i) {
        const int mm = (m0 - img * (HH * WW)) + wm * 112 + i * 16 + fr;
        const int oh = mm / WW;
        const int ow = mm - oh * WW;
        abase[i] = ((oh - oh0) * 58 + ow) * CIN;   // shorts (cell stride 128)
        aow[i]   = ow;
    }

    // B staging row bases (rows r0 and r0+128 of the 256-row B panel)
    const int r0 = t >> 2;
    const int bbase0 = r0 * KTOT;
    const int bbase1 = (r0 + 128) * KTOT;

    f32x4 acc[7][4];
#pragma unroll
    for (int i = 0; i < 7; ++i)
#pragma unroll
        for (int j = 0; j < 4; ++j) { f32x4 z = {0.f, 0.f, 0.f, 0.f}; acc[i][j] = z; }

    bf16x8 Aa[7], Ab[7], Ba[4], Bb[4];

#define STAGE_B(K, RG) do {                                                   \
        const int _kk  = (K) > 35 ? 35 : (K);                                 \
        const int _off = _kk * 32 + kcs * 8;                                  \
        short* _l = lds + B_BASE + (RG) * BREG_SZ;                            \
        async16(_l + w * 512,        bwt + bbase0 + _off);                    \
        async16(_l + 4096 + w * 512, bwt + bbase1 + _off);                    \
    } while (0)

    // A fragments for kh-phase K1 from the persistent window.
    // tap = K1>>2 (fh,fw), ch quarter q = K1&3; lane reads logical chunk
    // q*4+fq at cell (oh-oh0+fh, ow+fw); phys = logical ^ (iw&15).
#define RD_A(AF, K1) do {                                                     \
        const int _kk  = (K1) > 35 ? 35 : (K1);                               \
        const int _tap = _kk >> 2;                                            \
        const int _q   = _kk & 3;                                             \
        const int _fh  = (_tap * 11) >> 5;                                    \
        const int _fw  = _tap - 3 * _fh;                                      \
        const int _toff = (_fh * 58 + _fw) * CIN;                             \
        const int _q4 = (_q << 2) | fq;                                       \
        _Pragma("unroll")                                                     \
        for (int _i = 0; _i < 7; ++_i) {                                      \
            const int _phys = _q4 ^ ((aow[_i] + _fw) & 15);                   \
            (AF)[_i] = *(const bf16x8*)(lds + abase[_i] + _toff + (_phys << 3)); \
        }                                                                     \
    } while (0)

#define RD_B(BF, RG) do {                                                     \
        const short* _b = lds + B_BASE + (RG) * BREG_SZ + bfb;                \
        _Pragma("unroll")                                                     \
        for (int _j = 0; _j < 4; ++_j)                                        \
            (BF)[_j] = *(const bf16x8*)(_b + _j * 512 + laneoff);             \
    } while (0)

#define MM(AF, BF) do {                                                       \
        __builtin_amdgcn_s_setprio(1);                                        \
        _Pragma("unroll")                                                     \
        for (int _i = 0; _i < 7; ++_i)                                        \
            _Pragma("unroll")                                                 \
            for (int _j = 0; _j < 4; ++_j)                                    \
                acc[_i][_j] = __builtin_amdgcn_mfma_f32_16x16x32_bf16(        \
                    (AF)[_i], (BF)[_j], acc[_i][_j], 0, 0, 0);                \
        __builtin_amdgcn_s_setprio(0);                                        \
    } while (0)

    // phase: stage-B | prefetch next kh frags | 28 MFMA | VMWAIT(2) | barrier
#define PHZ(C, K, AFc, BFc, AFn, BFn) do {                                    \
        STAGE_B((K) + 3, (C) % 3);                                            \
        RD_A(AFn, (K) + 1);                                                   \
        RD_B(BFn, ((C) + 1) % 3);                                             \
        MM(AFc, BFc);                                                         \
        VMWAIT(2);                                                            \
        BARRIER();                                                            \
    } while (0)

    // ---- prologue A: reg-stage the 6x58x128 window from fp32 input.
    // Thread handles logical chunk L = j*512+t (8 channels at one cell);
    // loads 2x float4 (coalesced: 16 lanes cover 512 B), cvt, halo-zero,
    // ds_write_b128 to phys = L^(iw&15).  Clamped chunks duplicate 5567
    // (same value, benign).
#pragma unroll
    for (int j = 0; j < 11; ++j) {
        const int P    = j * 512 + t;
        const int Pc   = P > (AWIN_CHUNKS - 1) ? (AWIN_CHUNKS - 1) : P;
        const int cell = Pc >> 4;
        const int lch  = Pc & 15;
        const int dr   = cell / 58;
        const int iw   = cell - dr * 58;
        const int ri   = oh0 + dr - 1;          // input row
        const int ci   = iw - 1;                // input col
        bf16x8 v = (bf16x8)0;
        if (ri >= 0 && ri < HH && ci >= 0 && ci < WW) {
            const float* p = in + (((size_t)(img * HH + ri) * WW + ci) * CIN + lch * 8);
            const float4 x0 = *(const float4*)p;
            const float4 x1 = *(const float4*)(p + 4);
            v.s0 = f2bf(x0.x); v.s1 = f2bf(x0.y); v.s2 = f2bf(x0.z); v.s3 = f2bf(x0.w);
            v.s4 = f2bf(x1.x); v.s5 = f2bf(x1.y); v.s6 = f2bf(x1.z); v.s7 = f2bf(x1.w);
        }
        *(bf16x8*)(lds + (cell * 16 + (lch ^ (iw & 15))) * 8) = v;
    }
    // ---- prologue B: stage kh0..2
    STAGE_B(0, 0); STAGE_B(1, 1); STAGE_B(2, 2);
    VMWAIT(2);                 // drains B0+B1; leaves B2 in flight
    LGKMWAIT0();               // A ds_writes visible before barrier
    BARRIER();
    RD_A(Aa, 0); RD_B(Ba, 0);
    BARRIER();

    // ---- main loop: 36 phases, 6-phase static body (B regions mod 3,
    // frag sets mod 2)
#pragma unroll 1
    for (int jb = 0; jb < NPHASE; jb += 6) {
        PHZ(0, jb + 0, Aa, Ba, Ab, Bb);
        PHZ(1, jb + 1, Ab, Bb, Aa, Ba);
        PHZ(2, jb + 2, Aa, Ba, Ab, Bb);
        PHZ(3, jb + 3, Ab, Bb, Aa, Ba);
        PHZ(4, jb + 4, Aa, Ba, Ab, Bb);
        PHZ(5, jb + 5, Ab, Bb, Aa, Ba);
    }

    VMWAIT(0);   // all DMA (incl. clamped dummies) landed before block exits

    // ---- epilogue: bias + ReLU. D: col(N)=lane&15, row(M)=fq*4+reg (m89)
#pragma unroll
    for (int j = 0; j < 4; ++j) {
        const int n  = wn * 64 + j * 16 + fr;
        const float bj = bias[n];
#pragma unroll
        for (int i = 0; i < 7; ++i) {
            const int mr = m0 + wm * 112 + i * 16 + fq * 4;
#pragma unroll
            for (int r = 0; r < 4; ++r) {
                const float v = acc[i][j][r] + bj;
                out[(size_t)(mr + r) * COUT + n] = v > 0.f ? v : 0.f;
            }
        }
    }
#undef STAGE_B
#undef RD_A
#undef RD_B
#undef MM
#undef PHZ
}

extern "C" void kernel_launch(void* const* d_in, const int* in_sizes, int n_in,
                              void* d_out, int out_size, void* d_ws, size_t ws_size,
                              hipStream_t stream) {
    const float* in   = (const float*)d_in[0];
    const float* wgt  = (const float*)d_in[1];
    const float* bias = (const float*)d_in[2];
    float* out = (float*)d_out;

    short* wt = (short*)d_ws;

    pack_wgt<<<dim3(KTOT / 32, COUT / 32), 256, 0, stream>>>(wgt, wt);
    conv_mfma<<<NBLK, 512, 0, stream>>>(in, wt, bias, out);
}